// Round 8
// baseline (479.604 us; speedup 1.0000x reference)
//
#include <hip/hip_runtime.h>

// MHA fused pipeline for MI355X (gfx950), f16 MFMA + fp32 accumulate.
// Round 15:
//  - attn: DROP V LDS-staging (m169 / Common-mistake #7: per-head KV is
//    L2/L1-resident at S=2048 -- staging cache-fit data is pure overhead;
//    m169 measured +26% for exactly this on attn). vf now read directly
//    from global V^T (16 rows x 32B aligned runs -> L1-friendly; V-tile
//    16KB warms L1, 3 of 4 waves hit). No sVt writes, no vpre prefetch,
//    no aliasing fence -> compiler can hoist V reads above the softmax
//    VALU block for latency cover. K staging kept (b128-friendly).
//  - gemm_qkv: unchanged from R14 (256x192, 512 blocks = 2 full rounds,
//    single-barrier loop; 123.3us, MfmaUtil 34.7 -- six schedule variants
//    proved LDS/MFMA won't overlap in this structure; parked).
//
// ws layout (bytes):
//   xh     @ 0          : 4096x2048 f16  (x cast)
//   wqkvt  @ 16777216   : 6144x2048 f16  (Wqkv^T)   [dead after QKV gemm]
//   Oh     @ 16777216   : 4096x2048 f16  (attn out)  [overlays wqkvt]
//   Qh     @ 41943040   : [64 bh][2048][64] f16  (RoPE'd)
//   Kh     @ 58720256   : [64 bh][2048][64] f16  (RoPE'd)
//   Vth    @ 75497472   : [64 bh][64][2048] f16  (V^T)
//   woutt  @ 92274688   : 2048x2048 f16  (Wout^T)
//   total 100663296 B = 96 MB

typedef _Float16 half8 __attribute__((ext_vector_type(8)));
typedef _Float16 half4 __attribute__((ext_vector_type(4)));
typedef float floatx4 __attribute__((ext_vector_type(4)));

#define GLD_LDS16(gp, sp)                                        \
  __builtin_amdgcn_global_load_lds(                              \
      (__attribute__((address_space(1))) void*)(gp),             \
      (__attribute__((address_space(3))) void*)(sp), 16, 0, 0)

__device__ __forceinline__ floatx4 mfma16(half8 a, half8 b, floatx4 c) {
  return __builtin_amdgcn_mfma_f32_16x16x32_f16(a, b, c, 0, 0, 0);
}
__device__ __forceinline__ floatx4 mfma16k16(half4 a, half4 b, floatx4 c) {
  return __builtin_amdgcn_mfma_f32_16x16x16f16(a, b, c, 0, 0, 0);
}

// ---------------------------------------------------------------- cvt_x
__global__ __launch_bounds__(256) void cvt_x_kernel(const float* __restrict__ x,
                                                    _Float16* __restrict__ xh) {
  int idx = blockIdx.x * 256 + threadIdx.x;  // 8 elems each, 8.4M total
  const floatx4* p = (const floatx4*)x + (size_t)idx * 2;
  floatx4 a = p[0], b = p[1];
  half8 o;
#pragma unroll
  for (int j = 0; j < 4; ++j) { o[j] = (_Float16)a[j]; o[4 + j] = (_Float16)b[j]; }
  *((half8*)xh + idx) = o;
}

// ------------------------------------------------------- cvt + transpose W
// W (Kd x Nd) f32 row-major  ->  Wt (Nd x Kd) f16 row-major
__global__ __launch_bounds__(256) void cvt_wt_kernel(const float* __restrict__ W,
                                                     _Float16* __restrict__ Wt,
                                                     int Kd, int Nd) {
  __shared__ float tile[64][65];
  int n0 = blockIdx.x * 64, k0 = blockIdx.y * 64;
  int tid = threadIdx.x;
#pragma unroll
  for (int it = 0; it < 4; ++it) {
    int r = (tid >> 4) + it * 16;   // k-local
    int c = (tid & 15) * 4;         // n-local
    floatx4 v = *(const floatx4*)(W + (size_t)(k0 + r) * Nd + n0 + c);
    tile[r][c + 0] = v[0]; tile[r][c + 1] = v[1];
    tile[r][c + 2] = v[2]; tile[r][c + 3] = v[3];
  }
  __syncthreads();
#pragma unroll
  for (int it = 0; it < 2; ++it) {
    int r = (tid >> 3) + it * 32;   // n-local
    int c = (tid & 7) * 8;          // k-local
    half8 o;
#pragma unroll
    for (int j = 0; j < 8; ++j) o[j] = (_Float16)tile[c + j][r];
    *(half8*)(Wt + (size_t)(n0 + r) * Kd + k0 + c) = o;
  }
}

// --------------------------------------------- 256x192 1-barrier GEMM (QKV)
// C(256x192) = A(4096x2048) @ Bt(6144x2048)^T + bias, QKV epilogue.
// 8 waves = 4M x 2N; grid 32x16 = 512 blocks = 2 full rounds.
// (Unchanged from R14: 123.3us, MfmaUtil 34.7, conflicts 0.)
__global__ __launch_bounds__(512, 2) void gemm_qkv_kernel(
    const _Float16* __restrict__ A, const _Float16* __restrict__ Bt,
    const float* __restrict__ bias,
    _Float16* __restrict__ Qd, _Float16* __restrict__ Kkd,
    _Float16* __restrict__ Vd) {
  __shared__ __align__(16) _Float16 sA[2][16384];   // 256 x 64
  __shared__ __align__(16) _Float16 sB[2][12288];   // 192 x 64
  constexpr int KD = 2048;
  constexpr int NT = KD / 64;  // 32 K-tiles

  int tid = threadIdx.x, w = tid >> 6, l = tid & 63;
  int lr = l & 15, quad = l >> 4;
  int wr = w >> 1, wc = w & 1;
  int m0 = blockIdx.y * 256, n0 = blockIdx.x * 192;

  int csw0 = ((quad) ^ (lr & 7)) * 8;
  int csw1 = ((quad + 4) ^ (lr & 7)) * 8;

  const _Float16* pA[4];
  const _Float16* pB[3];
  {
    int rl = l >> 3;
    int cs = ((l & 7) ^ rl) * 8;
#pragma unroll
    for (int jj = 0; jj < 4; ++jj)
      pA[jj] = A + (size_t)(m0 + w * 32 + jj * 8 + rl) * KD + cs;
#pragma unroll
    for (int jj = 0; jj < 3; ++jj)
      pB[jj] = Bt + (size_t)(n0 + w * 24 + jj * 8 + rl) * KD + cs;
  }

#define STAGE_ALL(BUF, KT)                                                   \
  _Pragma("unroll") for (int jj = 0; jj < 4; ++jj)                           \
    GLD_LDS16(pA[jj] + (KT), &sA[BUF][(w * 32 + jj * 8) * 64]);              \
  _Pragma("unroll") for (int jj = 0; jj < 3; ++jj)                           \
    GLD_LDS16(pB[jj] + (KT), &sB[BUF][(w * 24 + jj * 8) * 64]);

  floatx4 z4 = {0.f, 0.f, 0.f, 0.f};
  floatx4 acc[4][6];
#pragma unroll
  for (int i = 0; i < 4; ++i)
#pragma unroll
    for (int j = 0; j < 6; ++j) acc[i][j] = z4;

  STAGE_ALL(0, 0);
  asm volatile("s_waitcnt vmcnt(0)" ::: "memory");
  __builtin_amdgcn_s_barrier();

  half8 af[4][2], bf[6][2];
#pragma unroll 2
  for (int t = 0; t < NT; ++t) {
    int buf = t & 1, nbuf = buf ^ 1;
    if (t + 1 < NT) { STAGE_ALL(nbuf, (t + 1) * 64); }
#pragma unroll
    for (int j = 0; j < 6; ++j) {
      int row_ = wc * 96 + j * 16 + lr;
      bf[j][0] = *(const half8*)&sB[buf][row_ * 64 + csw0];
      bf[j][1] = *(const half8*)&sB[buf][row_ * 64 + csw1];
    }
#pragma unroll
    for (int i = 0; i < 4; ++i) {
      int row_ = wr * 64 + i * 16 + lr;
      af[i][0] = *(const half8*)&sA[buf][row_ * 64 + csw0];
      af[i][1] = *(const half8*)&sA[buf][row_ * 64 + csw1];
    }
    __builtin_amdgcn_s_setprio(1);
#pragma unroll
    for (int j = 0; j < 6; ++j)
#pragma unroll
      for (int ks = 0; ks < 2; ++ks)
#pragma unroll
        for (int i = 0; i < 4; ++i)
          acc[i][j] = mfma16(af[i][ks], bf[j][ks], acc[i][j]);
    __builtin_amdgcn_s_setprio(0);
    asm volatile("s_waitcnt vmcnt(0)" ::: "memory");
    __builtin_amdgcn_s_barrier();
  }

  // ---- epilogue. C/D layout: col = lane&15, row = quad*4 + r.
  float bj[6];
#pragma unroll
  for (int j = 0; j < 6; ++j) bj[j] = bias[n0 + wc * 96 + j * 16 + lr];
  float freq = __expf(-(float)lr * 0.57564627324851148f);  // 10000^(-lr/16)
#pragma unroll
  for (int j = 0; j < 6; ++j) {
    int cb = wc * 96 + j * 16;
    int cg = n0 + cb;
    int which = cg >> 11;
    int d0 = cb & 63;  // n0 is 64-aligned (192*bx)
    int hh = (cg & 2047) >> 6;
    if (which == 2) {
      int dd = d0 + lr;
#pragma unroll
      for (int i = 0; i < 4; ++i) {
        int m = m0 + wr * 64 + i * 16 + quad * 4;
        int bb = m >> 11, tt = m & 2047;
        half4 h;
#pragma unroll
        for (int r = 0; r < 4; ++r) h[r] = (_Float16)(acc[i][j][r] + bj[j]);
        *(half4*)&Vd[(((size_t)(bb * 32 + hh)) * 64 + dd) * 2048 + tt] = h;
      }
    } else if (d0 == 0) {
      _Float16* dst = which ? Kkd : Qd;
#pragma unroll
      for (int i = 0; i < 4; ++i)
#pragma unroll
        for (int r = 0; r < 4; ++r) {
          int m = m0 + wr * 64 + i * 16 + quad * 4 + r;
          int bb = m >> 11, tt = m & 2047;
          float sn, cs2;
          __sincosf((float)tt * freq, &sn, &cs2);
          float x1 = acc[i][j][r] + bj[j];
          float x2 = acc[i][j + 1][r] + bj[j + 1];
          _Float16* row = dst + ((size_t)(bb * 32 + hh) * 2048 + (size_t)tt) * 64;
          row[lr] = (_Float16)(x1 * cs2 - x2 * sn);
          row[lr + 16] = (_Float16)(x1 * sn + x2 * cs2);
        }
    } else if (d0 >= 32) {
      _Float16* dst = which ? Kkd : Qd;
#pragma unroll
      for (int i = 0; i < 4; ++i)
#pragma unroll
        for (int r = 0; r < 4; ++r) {
          int m = m0 + wr * 64 + i * 16 + quad * 4 + r;
          int bb = m >> 11, tt = m & 2047;
          _Float16* row = dst + ((size_t)(bb * 32 + hh) * 2048 + (size_t)tt) * 64;
          row[d0 + lr] = (_Float16)(acc[i][j][r] + bj[j]);
        }
    }
  }
#undef STAGE_ALL
}

// ---------------------------------------------------------------- GEMM 128^2
// (kept for the out-projection.)
template <int MODE>
__global__ __launch_bounds__(256) void gemm_f16_kernel(
    const _Float16* __restrict__ A, const _Float16* __restrict__ Bt,
    const float* __restrict__ bias, int Kd, int Nd,
    _Float16* __restrict__ Qd, _Float16* __restrict__ Kkd,
    _Float16* __restrict__ Vd, float* __restrict__ Co) {
  __shared__ __align__(16) _Float16 sA[128 * 64];
  __shared__ __align__(16) _Float16 sB[128 * 64];
  int tid = threadIdx.x, w = tid >> 6, l = tid & 63;
  int lr = l & 15, lq = l >> 4;
  int m0 = blockIdx.y * 128, n0 = blockIdx.x * 128;
  int wrow = (w >> 1) * 64, wcol = (w & 1) * 64;

  floatx4 z4 = {0.f, 0.f, 0.f, 0.f};
  floatx4 acc[4][4];
#pragma unroll
  for (int i = 0; i < 4; ++i)
#pragma unroll
    for (int j = 0; j < 4; ++j) acc[i][j] = z4;

  int srow = l >> 3;              // row within 8-row chunk
  int slot = (l & 7) ^ srow;      // XOR-swizzled global k8-chunk
  const _Float16* aG = A + (size_t)(m0 + w * 32 + srow) * Kd + slot * 8;
  const _Float16* bG = Bt + (size_t)(n0 + w * 32 + srow) * Kd + slot * 8;
  _Float16* sAw = &sA[w * 2048];
  _Float16* sBw = &sB[w * 2048];

  for (int kt = 0; kt < Kd; kt += 64) {
#pragma unroll
    for (int t = 0; t < 4; ++t) {
      GLD_LDS16(aG + (size_t)t * 8 * Kd + kt, sAw + t * 512);
      GLD_LDS16(bG + (size_t)t * 8 * Kd + kt, sBw + t * 512);
    }
    __syncthreads();
#pragma unroll
    for (int ks = 0; ks < 2; ++ks) {
      half8 af[4], bf[4];
#pragma unroll
      for (int i = 0; i < 4; ++i) {
        int ar = wrow + i * 16 + lr;
        int br = wcol + i * 16 + lr;
        int sl = (((ks << 2) | lq) ^ (lr & 7)) * 8;
        af[i] = *(const half8*)&sA[ar * 64 + sl];
        bf[i] = *(const half8*)&sB[br * 64 + sl];
      }
#pragma unroll
      for (int i = 0; i < 4; ++i)
#pragma unroll
        for (int j = 0; j < 4; ++j) acc[i][j] = mfma16(af[i], bf[j], acc[i][j]);
    }
    __syncthreads();
  }

  if (MODE == 0) {
    // (unused in this round's launch; retained for completeness)
    int which = n0 >> 11;
    float bj[4];
#pragma unroll
    for (int j = 0; j < 4; ++j) bj[j] = bias[n0 + wcol + j * 16 + lr];
    int hh = ((n0 & 2047) + wcol) >> 6;
    if (which == 2) {
#pragma unroll
      for (int j = 0; j < 4; ++j) {
        int dd = j * 16 + lr;
#pragma unroll
        for (int i = 0; i < 4; ++i) {
          int m = m0 + wrow + i * 16 + lq * 4;
          int bb = m >> 11, t = m & 2047;
          half4 h;
#pragma unroll
          for (int r = 0; r < 4; ++r) h[r] = (_Float16)(acc[i][j][r] + bj[j]);
          *(half4*)&Vd[(((size_t)(bb * 32 + hh)) * 64 + dd) * 2048 + t] = h;
        }
      }
    } else {
      _Float16* dst = which ? Kkd : Qd;
      float freq = __expf(-(float)lr * 0.57564627324851148f);
#pragma unroll
      for (int i = 0; i < 4; ++i)
#pragma unroll
        for (int r = 0; r < 4; ++r) {
          int m = m0 + wrow + i * 16 + lq * 4 + r;
          int bb = m >> 11, t = m & 2047;
          float sn, cs;
          __sincosf((float)t * freq, &sn, &cs);
          float x1 = acc[i][0][r] + bj[0];
          float x2 = acc[i][1][r] + bj[1];
          _Float16* row = dst + ((size_t)(bb * 32 + hh) * 2048 + (size_t)t) * 64;
          row[lr]      = (_Float16)(x1 * cs - x2 * sn);
          row[lr + 16] = (_Float16)(x1 * sn + x2 * cs);
          row[lr + 32] = (_Float16)(acc[i][2][r] + bj[2]);
          row[lr + 48] = (_Float16)(acc[i][3][r] + bj[3]);
        }
    }
  } else {
#pragma unroll
    for (int j = 0; j < 4; ++j) {
      int n = n0 + wcol + j * 16 + lr;
      float bj = bias[n];
#pragma unroll
      for (int i = 0; i < 4; ++i)
#pragma unroll
        for (int r = 0; r < 4; ++r) {
          int m = m0 + wrow + i * 16 + lq * 4 + r;
          Co[(size_t)m * Nd + n] = acc[i][j][r] + bj;
        }
    }
  }
}

// ---------------------------------------------------------------- attention
// Flash-style causal attention, S^T formulation + register prefetch +
// PAIRED q-tiles (uniform 17 kv-iterations per block).
// R15: V is NOT LDS-staged -- vf read directly from global V^T (L1/L2
// resident; m169 precedent). K staging + double prefetch kept.
__global__ __launch_bounds__(256) void attn_kernel(
    const _Float16* __restrict__ Q, const _Float16* __restrict__ Kk,
    const _Float16* __restrict__ Vt, _Float16* __restrict__ O) {
  constexpr int S = 2048;
  int bh = blockIdx.x;
  int by = blockIdx.y;  // 0..7
  int bb = bh >> 5, hh = bh & 31;
  const _Float16* Qb = Q + (size_t)bh * S * 64;
  const _Float16* Kb = Kk + (size_t)bh * S * 64;
  const _Float16* Vb = Vt + (size_t)bh * 64 * S;

  __shared__ __align__(16) _Float16 sK[128 * 72];   // [kv][64+pad], reused as sO

  int tid = threadIdx.x, w = tid >> 6, l = tid & 63;
  int lr = l & 15, quad = l >> 4;

  int rk = tid >> 3, ck = (tid & 7) * 8;   // K: 32 rows x 64d per pass
  const _Float16* Kst = Kb + (size_t)rk * 64 + ck;

  int qts[2] = {15 - by, by};
  floatx4 z4 = {0.f, 0.f, 0.f, 0.f};

  for (int h = 0; h < 2; ++h) {
    int qt = qts[h];
    int q0 = qt * 128;

    half8 qf[2][2];  // [qtile][ks]
#pragma unroll
    for (int qtl = 0; qtl < 2; ++qtl)
#pragma unroll
      for (int ks = 0; ks < 2; ++ks) {
        half8 v = *(const half8*)(Qb + (size_t)(q0 + w * 32 + qtl * 16 + lr) * 64 +
                                  ks * 32 + quad * 8);
        qf[qtl][ks] = v * (_Float16)0.18033688f;  // 0.125 * log2(e)
      }

    floatx4 Oa[4][2];
    float m_i[2] = {-1e30f, -1e30f}, l_i[2] = {0.f, 0.f};
#pragma unroll
    for (int dt = 0; dt < 4; ++dt)
#pragma unroll
      for (int qtl = 0; qtl < 2; ++qtl) Oa[dt][qtl] = z4;

    half8 kpre[4];
#pragma unroll
    for (int it = 0; it < 4; ++it)
      kpre[it] = *(const half8*)(Kst + (size_t)it * 32 * 64);

    for (int jt = 0; jt <= qt; ++jt) {
#pragma unroll
      for (int it = 0; it < 4; ++it)
        *(half8*)&sK[(rk + it * 32) * 72 + ck] = kpre[it];
      if (jt < qt) {
        int kv1 = (jt + 1) * 128;
#pragma unroll
        for (int it = 0; it < 4; ++it)
          kpre[it] = *(const half8*)(Kst + (size_t)(kv1 + it * 32) * 64);
      }
      __syncthreads();

      floatx4 Sa[2][8];
#pragma unroll
      for (int qtl = 0; qtl < 2; ++qtl)
#pragma unroll
        for (int kvt = 0; kvt < 8; ++kvt) Sa[qtl][kvt] = z4;
      __builtin_amdgcn_s_setprio(1);
#pragma unroll
      for (int ks = 0; ks < 2; ++ks) {
#pragma unroll
        for (int kvt = 0; kvt < 8; ++kvt) {
          half8 kf = *(const half8*)&sK[(kvt * 16 + lr) * 72 + ks * 32 + quad * 8];
          Sa[0][kvt] = mfma16(kf, qf[0][ks], Sa[0][kvt]);
          Sa[1][kvt] = mfma16(kf, qf[1][ks], Sa[1][kvt]);
        }
      }
      __builtin_amdgcn_s_setprio(0);

      if (jt == qt) {
#pragma unroll
        for (int qtl = 0; qtl < 2; ++qtl) {
          int q_loc = w * 32 + qtl * 16 + lr;
#pragma unroll
          for (int kvt = 0; kvt < 8; ++kvt) {
            int kv_base = kvt * 16 + quad * 4;
#pragma unroll
            for (int r = 0; r < 4; ++r)
              if (kv_base + r > q_loc) Sa[qtl][kvt][r] = -1e30f;
          }
        }
      }

#pragma unroll
      for (int qtl = 0; qtl < 2; ++qtl) {
        float mx = Sa[qtl][0][0];
#pragma unroll
        for (int kvt = 0; kvt < 8; ++kvt)
#pragma unroll
          for (int r = 0; r < 4; ++r) mx = fmaxf(mx, Sa[qtl][kvt][r]);
        mx = fmaxf(mx, __shfl_xor(mx, 16));
        mx = fmaxf(mx, __shfl_xor(mx, 32));
        float mnew = fmaxf(m_i[qtl], mx);
        float alpha = __builtin_amdgcn_exp2f(m_i[qtl] - mnew);
        m_i[qtl] = mnew;
        float rs = 0.f;
#pragma unroll
        for (int kvt = 0; kvt < 8; ++kvt)
#pragma unroll
          for (int r = 0; r < 4; ++r) {
            float p = __builtin_amdgcn_exp2f(Sa[qtl][kvt][r] - mnew);
            Sa[qtl][kvt][r] = p;
            rs += p;
          }
        rs += __shfl_xor(rs, 16);
        rs += __shfl_xor(rs, 32);
        l_i[qtl] = l_i[qtl] * alpha + rs;
#pragma unroll
        for (int dt = 0; dt < 4; ++dt) Oa[dt][qtl] *= alpha;
      }

      // PV: vf direct from global V^T (row d = dt*16+lr, col jt*128+kv)
      __builtin_amdgcn_s_setprio(1);
#pragma unroll
      for (int kvt = 0; kvt < 8; ++kvt) {
        half4 vf[4];
#pragma unroll
        for (int dt = 0; dt < 4; ++dt)
          vf[dt] = *(const half4*)(Vb + (size_t)(dt * 16 + lr) * S + jt * 128 +
                                   kvt * 16 + quad * 4);
        half4 pf[2];
#pragma unroll
        for (int qtl = 0; qtl < 2; ++qtl) {
          pf[qtl][0] = (_Float16)Sa[qtl][kvt][0];
          pf[qtl][1] = (_Float16)Sa[qtl][kvt][1];
          pf[qtl][2] = (_Float16)Sa[qtl][kvt][2];
          pf[qtl][3] = (_Float16)Sa[qtl][kvt][3];
        }
#pragma unroll
        for (int dt = 0; dt < 4; ++dt)
#pragma unroll
          for (int qtl = 0; qtl < 2; ++qtl)
            Oa[dt][qtl] = mfma16k16(vf[dt], pf[qtl], Oa[dt][qtl]);
      }
      __builtin_amdgcn_s_setprio(0);
      __syncthreads();
    }

    float inv0 = 1.0f / l_i[0], inv1 = 1.0f / l_i[1];
#pragma unroll
    for (int dt = 0; dt < 4; ++dt)
#pragma unroll
      for (int qtl = 0; qtl < 2; ++qtl) {
        float inv = qtl ? inv1 : inv0;
        floatx4 o = Oa[dt][qtl];
        half4 hv;
        hv[0] = (_Float16)(o[0] * inv); hv[1] = (_Float16)(o[1] * inv);
        hv[2] = (_Float16)(o[2] * inv); hv[3] = (_Float16)(o[3] * inv);
        *(half4*)&sK[(w * 32 + qtl * 16 + lr) * 72 + dt * 16 + quad * 4] = hv;
      }
    __syncthreads();
#pragma unroll
    for (int it = 0; it < 2; ++it) {
      int row = (tid >> 2) + it * 64;
      int t = q0 + row;
      _Float16* orow = O + ((size_t)(bb * 2048 + t)) * 2048 + hh * 64;
#pragma unroll
      for (int cc = 0; cc < 2; ++cc) {
        int col = (tid & 3) * 16 + cc * 8;
        *(half8*)(orow + col) = *(const half8*)&sK[row * 72 + col];
      }
    }
    __syncthreads();
  }
}

// ---------------------------------------------------------------- launch
extern "C" void kernel_launch(void* const* d_in, const int* in_sizes, int n_in,
                              void* d_out, int out_size, void* d_ws, size_t ws_size,
                              hipStream_t stream) {
  (void)in_sizes; (void)n_in; (void)out_size; (void)ws_size;
  const float* x = (const float*)d_in[0];
  const float* Wqkv = (const float*)d_in[1];
  const float* bqkv = (const float*)d_in[2];
  const float* Wout = (const float*)d_in[3];
  const float* bout = (const float*)d_in[4];
  float* out = (float*)d_out;
  char* ws = (char*)d_ws;

  _Float16* xh    = (_Float16*)(ws + 0);
  _Float16* wqkvt = (_Float16*)(ws + 16777216);
  _Float16* Oh    = (_Float16*)(ws + 16777216);   // overlays wqkvt (dead)
  _Float16* Qh    = (_Float16*)(ws + 41943040);
  _Float16* Kh    = (_Float16*)(ws + 58720256);
  _Float16* Vth   = (_Float16*)(ws + 75497472);   // V^T
  _Float16* woutt = (_Float16*)(ws + 92274688);   // total 96 MB

  cvt_x_kernel<<<4096, 256, 0, stream>>>(x, xh);
  cvt_wt_kernel<<<dim3(96, 32), 256, 0, stream>>>(Wqkv, wqkvt, 2048, 6144);
  cvt_wt_kernel<<<dim3(32, 32), 256, 0, stream>>>(Wout, woutt, 2048, 2048);
  gemm_qkv_kernel<<<dim3(32, 16), 512, 0, stream>>>(xh, wqkvt, bqkv, Qh, Kh, Vth);
  attn_kernel<<<dim3(64, 8), 256, 0, stream>>>(Qh, Kh, Vth, Oh);
  gemm_f16_kernel<1><<<dim3(16, 32), 256, 0, stream>>>(
      Oh, woutt, bout, 2048, 2048, nullptr, nullptr, nullptr, out);
}

// Round 9
// 386.272 us; speedup vs baseline: 1.2416x; 1.2416x over previous
//
#include <hip/hip_runtime.h>

// MHA fused pipeline for MI355X (gfx950), f16 MFMA + fp32 accumulate.
// Round 16:
//  - attn: REVERT R15's V-direct-global (regressed 104->195us: PV's A-frag
//    layout V^T[d=lane&15][kv] makes direct loads a 16x32B-segment gather,
//    latency-bound, MfmaUtil 11/VALU 19/HBM 2.6 all idle). sVt LDS staging
//    restored exactly as R14.
//  - attn: ONE q-tile per block (was paired 2/block). Grid 64x16=1024
//    blocks -> 3 resident/CU (VGPR 148 caps 3 waves/SIMD; old grid 512 was
//    the binding limit at 2/CU). Total work unchanged; latency-bound kernel
//    gets 1.5x TLP. Long blocks (qt=15-by) launch first to bound the tail.
//  - gemm_qkv: unchanged (R14: 123.3us, MfmaUtil 34.7, 512 blocks = 2 full
//    rounds; six schedule variants showed LDS/MFMA won't overlap -- parked).
//
// ws layout (bytes):
//   xh     @ 0          : 4096x2048 f16  (x cast)
//   wqkvt  @ 16777216   : 6144x2048 f16  (Wqkv^T)   [dead after QKV gemm]
//   Oh     @ 16777216   : 4096x2048 f16  (attn out)  [overlays wqkvt]
//   Qh     @ 41943040   : [64 bh][2048][64] f16  (RoPE'd)
//   Kh     @ 58720256   : [64 bh][2048][64] f16  (RoPE'd)
//   Vth    @ 75497472   : [64 bh][64][2048] f16  (V^T)
//   woutt  @ 92274688   : 2048x2048 f16  (Wout^T)
//   total 100663296 B = 96 MB

typedef _Float16 half8 __attribute__((ext_vector_type(8)));
typedef _Float16 half4 __attribute__((ext_vector_type(4)));
typedef float floatx4 __attribute__((ext_vector_type(4)));

#define GLD_LDS16(gp, sp)                                        \
  __builtin_amdgcn_global_load_lds(                              \
      (__attribute__((address_space(1))) void*)(gp),             \
      (__attribute__((address_space(3))) void*)(sp), 16, 0, 0)

__device__ __forceinline__ floatx4 mfma16(half8 a, half8 b, floatx4 c) {
  return __builtin_amdgcn_mfma_f32_16x16x32_f16(a, b, c, 0, 0, 0);
}
__device__ __forceinline__ floatx4 mfma16k16(half4 a, half4 b, floatx4 c) {
  return __builtin_amdgcn_mfma_f32_16x16x16f16(a, b, c, 0, 0, 0);
}

// ---------------------------------------------------------------- cvt_x
__global__ __launch_bounds__(256) void cvt_x_kernel(const float* __restrict__ x,
                                                    _Float16* __restrict__ xh) {
  int idx = blockIdx.x * 256 + threadIdx.x;  // 8 elems each, 8.4M total
  const floatx4* p = (const floatx4*)x + (size_t)idx * 2;
  floatx4 a = p[0], b = p[1];
  half8 o;
#pragma unroll
  for (int j = 0; j < 4; ++j) { o[j] = (_Float16)a[j]; o[4 + j] = (_Float16)b[j]; }
  *((half8*)xh + idx) = o;
}

// ------------------------------------------------------- cvt + transpose W
// W (Kd x Nd) f32 row-major  ->  Wt (Nd x Kd) f16 row-major
__global__ __launch_bounds__(256) void cvt_wt_kernel(const float* __restrict__ W,
                                                     _Float16* __restrict__ Wt,
                                                     int Kd, int Nd) {
  __shared__ float tile[64][65];
  int n0 = blockIdx.x * 64, k0 = blockIdx.y * 64;
  int tid = threadIdx.x;
#pragma unroll
  for (int it = 0; it < 4; ++it) {
    int r = (tid >> 4) + it * 16;   // k-local
    int c = (tid & 15) * 4;         // n-local
    floatx4 v = *(const floatx4*)(W + (size_t)(k0 + r) * Nd + n0 + c);
    tile[r][c + 0] = v[0]; tile[r][c + 1] = v[1];
    tile[r][c + 2] = v[2]; tile[r][c + 3] = v[3];
  }
  __syncthreads();
#pragma unroll
  for (int it = 0; it < 2; ++it) {
    int r = (tid >> 3) + it * 32;   // n-local
    int c = (tid & 7) * 8;          // k-local
    half8 o;
#pragma unroll
    for (int j = 0; j < 8; ++j) o[j] = (_Float16)tile[c + j][r];
    *(half8*)(Wt + (size_t)(n0 + r) * Kd + k0 + c) = o;
  }
}

// --------------------------------------------- 256x192 1-barrier GEMM (QKV)
// C(256x192) = A(4096x2048) @ Bt(6144x2048)^T + bias, QKV epilogue.
// 8 waves = 4M x 2N; grid 32x16 = 512 blocks = 2 full rounds.
// (Unchanged from R14: 123.3us, MfmaUtil 34.7, conflicts 0.)
__global__ __launch_bounds__(512, 2) void gemm_qkv_kernel(
    const _Float16* __restrict__ A, const _Float16* __restrict__ Bt,
    const float* __restrict__ bias,
    _Float16* __restrict__ Qd, _Float16* __restrict__ Kkd,
    _Float16* __restrict__ Vd) {
  __shared__ __align__(16) _Float16 sA[2][16384];   // 256 x 64
  __shared__ __align__(16) _Float16 sB[2][12288];   // 192 x 64
  constexpr int KD = 2048;
  constexpr int NT = KD / 64;  // 32 K-tiles

  int tid = threadIdx.x, w = tid >> 6, l = tid & 63;
  int lr = l & 15, quad = l >> 4;
  int wr = w >> 1, wc = w & 1;
  int m0 = blockIdx.y * 256, n0 = blockIdx.x * 192;

  int csw0 = ((quad) ^ (lr & 7)) * 8;
  int csw1 = ((quad + 4) ^ (lr & 7)) * 8;

  const _Float16* pA[4];
  const _Float16* pB[3];
  {
    int rl = l >> 3;
    int cs = ((l & 7) ^ rl) * 8;
#pragma unroll
    for (int jj = 0; jj < 4; ++jj)
      pA[jj] = A + (size_t)(m0 + w * 32 + jj * 8 + rl) * KD + cs;
#pragma unroll
    for (int jj = 0; jj < 3; ++jj)
      pB[jj] = Bt + (size_t)(n0 + w * 24 + jj * 8 + rl) * KD + cs;
  }

#define STAGE_ALL(BUF, KT)                                                   \
  _Pragma("unroll") for (int jj = 0; jj < 4; ++jj)                           \
    GLD_LDS16(pA[jj] + (KT), &sA[BUF][(w * 32 + jj * 8) * 64]);              \
  _Pragma("unroll") for (int jj = 0; jj < 3; ++jj)                           \
    GLD_LDS16(pB[jj] + (KT), &sB[BUF][(w * 24 + jj * 8) * 64]);

  floatx4 z4 = {0.f, 0.f, 0.f, 0.f};
  floatx4 acc[4][6];
#pragma unroll
  for (int i = 0; i < 4; ++i)
#pragma unroll
    for (int j = 0; j < 6; ++j) acc[i][j] = z4;

  STAGE_ALL(0, 0);
  asm volatile("s_waitcnt vmcnt(0)" ::: "memory");
  __builtin_amdgcn_s_barrier();

  half8 af[4][2], bf[6][2];
#pragma unroll 2
  for (int t = 0; t < NT; ++t) {
    int buf = t & 1, nbuf = buf ^ 1;
    if (t + 1 < NT) { STAGE_ALL(nbuf, (t + 1) * 64); }
#pragma unroll
    for (int j = 0; j < 6; ++j) {
      int row_ = wc * 96 + j * 16 + lr;
      bf[j][0] = *(const half8*)&sB[buf][row_ * 64 + csw0];
      bf[j][1] = *(const half8*)&sB[buf][row_ * 64 + csw1];
    }
#pragma unroll
    for (int i = 0; i < 4; ++i) {
      int row_ = wr * 64 + i * 16 + lr;
      af[i][0] = *(const half8*)&sA[buf][row_ * 64 + csw0];
      af[i][1] = *(const half8*)&sA[buf][row_ * 64 + csw1];
    }
    __builtin_amdgcn_s_setprio(1);
#pragma unroll
    for (int j = 0; j < 6; ++j)
#pragma unroll
      for (int ks = 0; ks < 2; ++ks)
#pragma unroll
        for (int i = 0; i < 4; ++i)
          acc[i][j] = mfma16(af[i][ks], bf[j][ks], acc[i][j]);
    __builtin_amdgcn_s_setprio(0);
    asm volatile("s_waitcnt vmcnt(0)" ::: "memory");
    __builtin_amdgcn_s_barrier();
  }

  // ---- epilogue. C/D layout: col = lane&15, row = quad*4 + r.
  float bj[6];
#pragma unroll
  for (int j = 0; j < 6; ++j) bj[j] = bias[n0 + wc * 96 + j * 16 + lr];
  float freq = __expf(-(float)lr * 0.57564627324851148f);  // 10000^(-lr/16)
#pragma unroll
  for (int j = 0; j < 6; ++j) {
    int cb = wc * 96 + j * 16;
    int cg = n0 + cb;
    int which = cg >> 11;
    int d0 = cb & 63;  // n0 is 64-aligned (192*bx)
    int hh = (cg & 2047) >> 6;
    if (which == 2) {
      int dd = d0 + lr;
#pragma unroll
      for (int i = 0; i < 4; ++i) {
        int m = m0 + wr * 64 + i * 16 + quad * 4;
        int bb = m >> 11, tt = m & 2047;
        half4 h;
#pragma unroll
        for (int r = 0; r < 4; ++r) h[r] = (_Float16)(acc[i][j][r] + bj[j]);
        *(half4*)&Vd[(((size_t)(bb * 32 + hh)) * 64 + dd) * 2048 + tt] = h;
      }
    } else if (d0 == 0) {
      _Float16* dst = which ? Kkd : Qd;
#pragma unroll
      for (int i = 0; i < 4; ++i)
#pragma unroll
        for (int r = 0; r < 4; ++r) {
          int m = m0 + wr * 64 + i * 16 + quad * 4 + r;
          int bb = m >> 11, tt = m & 2047;
          float sn, cs2;
          __sincosf((float)tt * freq, &sn, &cs2);
          float x1 = acc[i][j][r] + bj[j];
          float x2 = acc[i][j + 1][r] + bj[j + 1];
          _Float16* row = dst + ((size_t)(bb * 32 + hh) * 2048 + (size_t)tt) * 64;
          row[lr] = (_Float16)(x1 * cs2 - x2 * sn);
          row[lr + 16] = (_Float16)(x1 * sn + x2 * cs2);
        }
    } else if (d0 >= 32) {
      _Float16* dst = which ? Kkd : Qd;
#pragma unroll
      for (int i = 0; i < 4; ++i)
#pragma unroll
        for (int r = 0; r < 4; ++r) {
          int m = m0 + wr * 64 + i * 16 + quad * 4 + r;
          int bb = m >> 11, tt = m & 2047;
          _Float16* row = dst + ((size_t)(bb * 32 + hh) * 2048 + (size_t)tt) * 64;
          row[d0 + lr] = (_Float16)(acc[i][j][r] + bj[j]);
        }
    }
  }
#undef STAGE_ALL
}

// ---------------------------------------------------------------- GEMM 128^2
// (kept for the out-projection.)
template <int MODE>
__global__ __launch_bounds__(256) void gemm_f16_kernel(
    const _Float16* __restrict__ A, const _Float16* __restrict__ Bt,
    const float* __restrict__ bias, int Kd, int Nd,
    _Float16* __restrict__ Qd, _Float16* __restrict__ Kkd,
    _Float16* __restrict__ Vd, float* __restrict__ Co) {
  __shared__ __align__(16) _Float16 sA[128 * 64];
  __shared__ __align__(16) _Float16 sB[128 * 64];
  int tid = threadIdx.x, w = tid >> 6, l = tid & 63;
  int lr = l & 15, lq = l >> 4;
  int m0 = blockIdx.y * 128, n0 = blockIdx.x * 128;
  int wrow = (w >> 1) * 64, wcol = (w & 1) * 64;

  floatx4 z4 = {0.f, 0.f, 0.f, 0.f};
  floatx4 acc[4][4];
#pragma unroll
  for (int i = 0; i < 4; ++i)
#pragma unroll
    for (int j = 0; j < 4; ++j) acc[i][j] = z4;

  int srow = l >> 3;              // row within 8-row chunk
  int slot = (l & 7) ^ srow;      // XOR-swizzled global k8-chunk
  const _Float16* aG = A + (size_t)(m0 + w * 32 + srow) * Kd + slot * 8;
  const _Float16* bG = Bt + (size_t)(n0 + w * 32 + srow) * Kd + slot * 8;
  _Float16* sAw = &sA[w * 2048];
  _Float16* sBw = &sB[w * 2048];

  for (int kt = 0; kt < Kd; kt += 64) {
#pragma unroll
    for (int t = 0; t < 4; ++t) {
      GLD_LDS16(aG + (size_t)t * 8 * Kd + kt, sAw + t * 512);
      GLD_LDS16(bG + (size_t)t * 8 * Kd + kt, sBw + t * 512);
    }
    __syncthreads();
#pragma unroll
    for (int ks = 0; ks < 2; ++ks) {
      half8 af[4], bf[4];
#pragma unroll
      for (int i = 0; i < 4; ++i) {
        int ar = wrow + i * 16 + lr;
        int br = wcol + i * 16 + lr;
        int sl = (((ks << 2) | lq) ^ (lr & 7)) * 8;
        af[i] = *(const half8*)&sA[ar * 64 + sl];
        bf[i] = *(const half8*)&sB[br * 64 + sl];
      }
#pragma unroll
      for (int i = 0; i < 4; ++i)
#pragma unroll
        for (int j = 0; j < 4; ++j) acc[i][j] = mfma16(af[i], bf[j], acc[i][j]);
    }
    __syncthreads();
  }

  if (MODE == 0) {
    // (unused in this round's launch; retained for completeness)
    int which = n0 >> 11;
    float bj[4];
#pragma unroll
    for (int j = 0; j < 4; ++j) bj[j] = bias[n0 + wcol + j * 16 + lr];
    int hh = ((n0 & 2047) + wcol) >> 6;
    if (which == 2) {
#pragma unroll
      for (int j = 0; j < 4; ++j) {
        int dd = j * 16 + lr;
#pragma unroll
        for (int i = 0; i < 4; ++i) {
          int m = m0 + wrow + i * 16 + lq * 4;
          int bb = m >> 11, t = m & 2047;
          half4 h;
#pragma unroll
          for (int r = 0; r < 4; ++r) h[r] = (_Float16)(acc[i][j][r] + bj[j]);
          *(half4*)&Vd[(((size_t)(bb * 32 + hh)) * 64 + dd) * 2048 + t] = h;
        }
      }
    } else {
      _Float16* dst = which ? Kkd : Qd;
      float freq = __expf(-(float)lr * 0.57564627324851148f);
#pragma unroll
      for (int i = 0; i < 4; ++i)
#pragma unroll
        for (int r = 0; r < 4; ++r) {
          int m = m0 + wrow + i * 16 + lq * 4 + r;
          int bb = m >> 11, t = m & 2047;
          float sn, cs;
          __sincosf((float)t * freq, &sn, &cs);
          float x1 = acc[i][0][r] + bj[0];
          float x2 = acc[i][1][r] + bj[1];
          _Float16* row = dst + ((size_t)(bb * 32 + hh) * 2048 + (size_t)t) * 64;
          row[lr]      = (_Float16)(x1 * cs - x2 * sn);
          row[lr + 16] = (_Float16)(x1 * sn + x2 * cs);
          row[lr + 32] = (_Float16)(acc[i][2][r] + bj[2]);
          row[lr + 48] = (_Float16)(acc[i][3][r] + bj[3]);
        }
    }
  } else {
#pragma unroll
    for (int j = 0; j < 4; ++j) {
      int n = n0 + wcol + j * 16 + lr;
      float bj = bias[n];
#pragma unroll
      for (int i = 0; i < 4; ++i)
#pragma unroll
        for (int r = 0; r < 4; ++r) {
          int m = m0 + wrow + i * 16 + lq * 4 + r;
          Co[(size_t)m * Nd + n] = acc[i][j][r] + bj;
        }
    }
  }
}

// ---------------------------------------------------------------- attention
// Flash-style causal attention, S^T formulation + register prefetch.
// R16: ONE q-tile per block; grid 64 x 16, qt = 15 - blockIdx.y so the
// longest blocks (17..1 kv-iters) launch first. 3 blocks/CU resident
// (VGPR-capped) vs 2 before -- TLP for a latency-bound kernel.
// V LDS staging (sVt) restored exactly as R14 (R15's direct-global V was
// a 16-segment gather; regressed 104->195us).
__global__ __launch_bounds__(256) void attn_kernel(
    const _Float16* __restrict__ Q, const _Float16* __restrict__ Kk,
    const _Float16* __restrict__ Vt, _Float16* __restrict__ O) {
  constexpr int S = 2048;
  int bh = blockIdx.x;
  int qt = 15 - blockIdx.y;  // long blocks first
  int bb = bh >> 5, hh = bh & 31;
  const _Float16* Qb = Q + (size_t)bh * S * 64;
  const _Float16* Kb = Kk + (size_t)bh * S * 64;
  const _Float16* Vb = Vt + (size_t)bh * 64 * S;

  __shared__ __align__(16) _Float16 sK[128 * 72];   // [kv][64+pad], reused as sO
  __shared__ __align__(16) _Float16 sVt[64 * 136];  // [d][128+pad]

  int tid = threadIdx.x, w = tid >> 6, l = tid & 63;
  int lr = l & 15, quad = l >> 4;

  int rk = tid >> 3, ck = (tid & 7) * 8;   // K: 32 rows x 64d per pass
  int rv = tid >> 4, cv = (tid & 15) * 8;  // Vt: 16 rows x 128kv per pass
  const _Float16* Kst = Kb + (size_t)rk * 64 + ck;
  const _Float16* Vst = Vb + (size_t)rv * S + cv;

  floatx4 z4 = {0.f, 0.f, 0.f, 0.f};
  int q0 = qt * 128;

  half8 qf[2][2];  // [qtile][ks]
#pragma unroll
  for (int qtl = 0; qtl < 2; ++qtl)
#pragma unroll
    for (int ks = 0; ks < 2; ++ks) {
      half8 v = *(const half8*)(Qb + (size_t)(q0 + w * 32 + qtl * 16 + lr) * 64 +
                                ks * 32 + quad * 8);
      qf[qtl][ks] = v * (_Float16)0.18033688f;  // 0.125 * log2(e)
    }

  floatx4 Oa[4][2];
  float m_i[2] = {-1e30f, -1e30f}, l_i[2] = {0.f, 0.f};
#pragma unroll
  for (int dt = 0; dt < 4; ++dt)
#pragma unroll
    for (int qtl = 0; qtl < 2; ++qtl) Oa[dt][qtl] = z4;

  half8 kpre[4], vpre[4];
#pragma unroll
  for (int it = 0; it < 4; ++it) {
    kpre[it] = *(const half8*)(Kst + (size_t)it * 32 * 64);
    vpre[it] = *(const half8*)(Vst + (size_t)it * 16 * S);
  }

  for (int jt = 0; jt <= qt; ++jt) {
#pragma unroll
    for (int it = 0; it < 4; ++it) {
      *(half8*)&sK[(rk + it * 32) * 72 + ck] = kpre[it];
      *(half8*)&sVt[(rv + it * 16) * 136 + cv] = vpre[it];
    }
    if (jt < qt) {
      int kv1 = (jt + 1) * 128;
#pragma unroll
      for (int it = 0; it < 4; ++it) {
        kpre[it] = *(const half8*)(Kst + (size_t)(kv1 + it * 32) * 64);
        vpre[it] = *(const half8*)(Vst + kv1 + (size_t)it * 16 * S);
      }
    }
    __syncthreads();

    floatx4 Sa[2][8];
#pragma unroll
    for (int qtl = 0; qtl < 2; ++qtl)
#pragma unroll
      for (int kvt = 0; kvt < 8; ++kvt) Sa[qtl][kvt] = z4;
    __builtin_amdgcn_s_setprio(1);
#pragma unroll
    for (int ks = 0; ks < 2; ++ks) {
#pragma unroll
      for (int kvt = 0; kvt < 8; ++kvt) {
        half8 kf = *(const half8*)&sK[(kvt * 16 + lr) * 72 + ks * 32 + quad * 8];
        Sa[0][kvt] = mfma16(kf, qf[0][ks], Sa[0][kvt]);
        Sa[1][kvt] = mfma16(kf, qf[1][ks], Sa[1][kvt]);
      }
    }
    __builtin_amdgcn_s_setprio(0);

    if (jt == qt) {
#pragma unroll
      for (int qtl = 0; qtl < 2; ++qtl) {
        int q_loc = w * 32 + qtl * 16 + lr;
#pragma unroll
        for (int kvt = 0; kvt < 8; ++kvt) {
          int kv_base = kvt * 16 + quad * 4;
#pragma unroll
          for (int r = 0; r < 4; ++r)
            if (kv_base + r > q_loc) Sa[qtl][kvt][r] = -1e30f;
        }
      }
    }

#pragma unroll
    for (int qtl = 0; qtl < 2; ++qtl) {
      float mx = Sa[qtl][0][0];
#pragma unroll
      for (int kvt = 0; kvt < 8; ++kvt)
#pragma unroll
        for (int r = 0; r < 4; ++r) mx = fmaxf(mx, Sa[qtl][kvt][r]);
      mx = fmaxf(mx, __shfl_xor(mx, 16));
      mx = fmaxf(mx, __shfl_xor(mx, 32));
      float mnew = fmaxf(m_i[qtl], mx);
      float alpha = __builtin_amdgcn_exp2f(m_i[qtl] - mnew);
      m_i[qtl] = mnew;
      float rs = 0.f;
#pragma unroll
      for (int kvt = 0; kvt < 8; ++kvt)
#pragma unroll
        for (int r = 0; r < 4; ++r) {
          float p = __builtin_amdgcn_exp2f(Sa[qtl][kvt][r] - mnew);
          Sa[qtl][kvt][r] = p;
          rs += p;
        }
      rs += __shfl_xor(rs, 16);
      rs += __shfl_xor(rs, 32);
      l_i[qtl] = l_i[qtl] * alpha + rs;
#pragma unroll
      for (int dt = 0; dt < 4; ++dt) Oa[dt][qtl] *= alpha;
    }

    __builtin_amdgcn_s_setprio(1);
#pragma unroll
    for (int kvt = 0; kvt < 8; ++kvt) {
      half4 vf[4];
#pragma unroll
      for (int dt = 0; dt < 4; ++dt)
        vf[dt] = *(const half4*)&sVt[(dt * 16 + lr) * 136 + kvt * 16 + quad * 4];
      half4 pf[2];
#pragma unroll
      for (int qtl = 0; qtl < 2; ++qtl) {
        pf[qtl][0] = (_Float16)Sa[qtl][kvt][0];
        pf[qtl][1] = (_Float16)Sa[qtl][kvt][1];
        pf[qtl][2] = (_Float16)Sa[qtl][kvt][2];
        pf[qtl][3] = (_Float16)Sa[qtl][kvt][3];
      }
#pragma unroll
      for (int dt = 0; dt < 4; ++dt)
#pragma unroll
        for (int qtl = 0; qtl < 2; ++qtl)
          Oa[dt][qtl] = mfma16k16(vf[dt], pf[qtl], Oa[dt][qtl]);
    }
    __builtin_amdgcn_s_setprio(0);
    __syncthreads();
  }

  float inv0 = 1.0f / l_i[0], inv1 = 1.0f / l_i[1];
#pragma unroll
  for (int dt = 0; dt < 4; ++dt)
#pragma unroll
    for (int qtl = 0; qtl < 2; ++qtl) {
      float inv = qtl ? inv1 : inv0;
      floatx4 o = Oa[dt][qtl];
      half4 hv;
      hv[0] = (_Float16)(o[0] * inv); hv[1] = (_Float16)(o[1] * inv);
      hv[2] = (_Float16)(o[2] * inv); hv[3] = (_Float16)(o[3] * inv);
      *(half4*)&sK[(w * 32 + qtl * 16 + lr) * 72 + dt * 16 + quad * 4] = hv;
    }
  __syncthreads();
#pragma unroll
  for (int it = 0; it < 2; ++it) {
    int row = (tid >> 2) + it * 64;
    int t = q0 + row;
    _Float16* orow = O + ((size_t)(bb * 2048 + t)) * 2048 + hh * 64;
#pragma unroll
    for (int cc = 0; cc < 2; ++cc) {
      int col = (tid & 3) * 16 + cc * 8;
      *(half8*)(orow + col) = *(const half8*)&sK[row * 72 + col];
    }
  }
}

// ---------------------------------------------------------------- launch
extern "C" void kernel_launch(void* const* d_in, const int* in_sizes, int n_in,
                              void* d_out, int out_size, void* d_ws, size_t ws_size,
                              hipStream_t stream) {
  (void)in_sizes; (void)n_in; (void)out_size; (void)ws_size;
  const float* x = (const float*)d_in[0];
  const float* Wqkv = (const float*)d_in[1];
  const float* bqkv = (const float*)d_in[2];
  const float* Wout = (const float*)d_in[3];
  const float* bout = (const float*)d_in[4];
  float* out = (float*)d_out;
  char* ws = (char*)d_ws;

  _Float16* xh    = (_Float16*)(ws + 0);
  _Float16* wqkvt = (_Float16*)(ws + 16777216);
  _Float16* Oh    = (_Float16*)(ws + 16777216);   // overlays wqkvt (dead)
  _Float16* Qh    = (_Float16*)(ws + 41943040);
  _Float16* Kh    = (_Float16*)(ws + 58720256);
  _Float16* Vth   = (_Float16*)(ws + 75497472);   // V^T
  _Float16* woutt = (_Float16*)(ws + 92274688);   // total 96 MB

  cvt_x_kernel<<<4096, 256, 0, stream>>>(x, xh);
  cvt_wt_kernel<<<dim3(96, 32), 256, 0, stream>>>(Wqkv, wqkvt, 2048, 6144);
  cvt_wt_kernel<<<dim3(32, 32), 256, 0, stream>>>(Wout, woutt, 2048, 2048);
  gemm_qkv_kernel<<<dim3(32, 16), 512, 0, stream>>>(xh, wqkvt, bqkv, Qh, Kh, Vth);
  attn_kernel<<<dim3(64, 16), 256, 0, stream>>>(Qh, Kh, Vth, Oh);
  gemm_f16_kernel<1><<<dim3(16, 32), 256, 0, stream>>>(
      Oh, woutt, bout, 2048, 2048, nullptr, nullptr, nullptr, out);
}